// Round 20
// baseline (106.144 us; speedup 1.0000x reference)
//
#include <hip/hip_runtime.h>
#include <hip/hip_bf16.h>
#include <hip/hip_fp8.h>

#define TWO_N 8192
#define NHALF 4096
#define D 256
#define NTILE 64            // 8192 / 128 tiles per dimension
#define BLK_BYTES 32768     // bytes per 128-row block: 128 rows * 256 fp8
static constexpr float INV_T = 2.0f; // 1 / 0.5

typedef __attribute__((ext_vector_type(4))) float f32x4;

#define AS1 __attribute__((address_space(1)))
#define AS3 __attribute__((address_space(3)))

// pack 4 floats -> 4 OCP e4m3 bytes
__device__ __forceinline__ unsigned int pack4_e4m3(float a, float b, float c, float d) {
#if __has_builtin(__builtin_amdgcn_cvt_pk_fp8_f32)
    int p = 0;
    p = __builtin_amdgcn_cvt_pk_fp8_f32(a, b, p, false);  // bytes 0,1
    p = __builtin_amdgcn_cvt_pk_fp8_f32(c, d, p, true);   // bytes 2,3
    return (unsigned int)p;
#else
    __hip_fp8_e4m3 qa(a), qb(b), qc(c), qd(d);
    return (unsigned int)qa.__x | ((unsigned int)qb.__x << 8) |
           ((unsigned int)qc.__x << 16) | ((unsigned int)qd.__x << 24);
#endif
}

// ------ kernel 1 (R15-exact): normalize + positive-pair sim, fp8 blocked ----
// znb8 layout (bytes): [rowblock(64)][kstep(4)][kchunk(8)][row(128)][e(8)]
__global__ __launch_bounds__(256) void norm_pos_kernel(
        const float* __restrict__ z_i, const float* __restrict__ z_j,
        unsigned char* __restrict__ znb, float* __restrict__ sim_pos,
        float* __restrict__ denom, float* __restrict__ facc,
        int* __restrict__ ftick) {
    const int wid = threadIdx.x >> 6, lane = threadIdx.x & 63;
    const int i = blockIdx.x * 4 + wid;  // 0..4095
    if (blockIdx.x == 0 && threadIdx.x == 0) { facc[0] = 0.0f; ftick[0] = 0; }
    const float4 vi = *reinterpret_cast<const float4*>(z_i + (size_t)i * D + lane * 4);
    const float4 vj = *reinterpret_cast<const float4*>(z_j + (size_t)i * D + lane * 4);
    float ssi = vi.x * vi.x + vi.y * vi.y + vi.z * vi.z + vi.w * vi.w;
    float ssj = vj.x * vj.x + vj.y * vj.y + vj.z * vj.z + vj.w * vj.w;
    float dt  = vi.x * vj.x + vi.y * vj.y + vi.z * vj.z + vi.w * vj.w;
    #pragma unroll
    for (int off = 32; off; off >>= 1) {
        ssi += __shfl_xor(ssi, off);
        ssj += __shfl_xor(ssj, off);
        dt  += __shfl_xor(dt,  off);
    }
    const float ri = rsqrtf(ssi), rj = rsqrtf(ssj);
    const unsigned int pi = pack4_e4m3(vi.x * ri, vi.y * ri, vi.z * ri, vi.w * ri);
    const unsigned int pj = pack4_e4m3(vj.x * rj, vj.y * rj, vj.z * rj, vj.w * rj);
    // lane covers k = lane*4 .. lane*4+3:
    //   kstep = lane>>4, kchunk = (lane>>1)&7, e = (lane&1)*4
    const size_t sub = (size_t)(lane >> 4) * 8192 + (size_t)((lane >> 1) & 7) * 1024
                     + (size_t)(i & 127) * 8 + (lane & 1) * 4;
    const int i2 = i + NHALF;
    *reinterpret_cast<unsigned int*>(znb + (size_t)(i  >> 7) * BLK_BYTES + sub) = pi;
    *reinterpret_cast<unsigned int*>(znb + (size_t)(i2 >> 7) * BLK_BYTES + sub) = pj;
    if (lane == 0) {
        const float sp = dt * ri * rj * INV_T;
        sim_pos[i] = sp;
        sim_pos[i + NHALF] = sp;   // symmetric
        denom[i] = 0.0f;
        denom[i + NHALF] = 0.0f;
    }
}

// ======== shared GEMM loop (R15-exact), used by production and probes ========
#define GEMM_BODY                                                                 \
    __shared__ unsigned char As[3][8192];                                         \
    __shared__ unsigned char Bs[3][8192];                                         \
    const int tid  = threadIdx.x;                                                 \
    const int lane = tid & 63;                                                    \
    const int wid  = tid >> 6;                                                    \
    const int wr   = wid >> 1;                                                    \
    const int wc   = wid & 1;                                                     \
    const int r16  = lane & 15;                                                   \
    const int kgrp = lane >> 4;                                                   \
    const int row0 = tr * 128;                                                    \
    const int col0 = tc * 128;                                                    \
    const unsigned char* gA = znb + (size_t)tr * BLK_BYTES + tid * 16;            \
    const unsigned char* gB = znb + (size_t)tc * BLK_BYTES + tid * 16;            \
    const int dst = wid * 1024;                                                   \
    f32x4 acc[4][4];                                                              \
    _Pragma("unroll")                                                             \
    for (int m = 0; m < 4; ++m)                                                   \
        _Pragma("unroll")                                                         \
        for (int n = 0; n < 4; ++n) {                                             \
            f32x4 z = {0.f, 0.f, 0.f, 0.f};                                       \
            acc[m][n] = z;                                                        \
        }                                                                         \
    STAGE(0, 0);                                                                  \
    STAGE(1, 8192);                                                               \
    _Pragma("unroll")                                                             \
    for (int ks = 0; ks < 4; ++ks) {                                              \
        const int cur = ks % 3;                                                   \
        if (ks < 3) asm volatile("s_waitcnt vmcnt(8)" ::: "memory");              \
        else        asm volatile("s_waitcnt vmcnt(0)" ::: "memory");              \
        __builtin_amdgcn_s_barrier();                                             \
        asm volatile("" ::: "memory");                                            \
        if (ks < 2) STAGE((ks + 2) % 3, (ks + 2) * 8192);                         \
        _Pragma("unroll")                                                         \
        for (int s = 0; s < 2; ++s) {                                             \
            long a[4], b[4];                                                      \
            _Pragma("unroll")                                                     \
            for (int m = 0; m < 4; ++m)                                           \
                a[m] = *reinterpret_cast<const long*>(                            \
                    As[cur] + (((s * 4 + kgrp) * 128) + wr * 64 + m * 16 + r16) * 8); \
            _Pragma("unroll")                                                     \
            for (int n = 0; n < 4; ++n)                                           \
                b[n] = *reinterpret_cast<const long*>(                            \
                    Bs[cur] + (((s * 4 + kgrp) * 128) + wc * 64 + n * 16 + r16) * 8); \
            _Pragma("unroll")                                                     \
            for (int m = 0; m < 4; ++m)                                           \
                _Pragma("unroll")                                                 \
                for (int n = 0; n < 4; ++n)                                       \
                    acc[m][n] = __builtin_amdgcn_mfma_f32_16x16x32_fp8_fp8(       \
                        a[m], b[n], acc[m][n], 0, 0, 0);                          \
        }                                                                         \
    }

#define STAGE(buf, koff)                                                          \
    do {                                                                          \
        __builtin_amdgcn_global_load_lds((const AS1 void*)(gA + (koff)),          \
            (AS3 void*)(As[buf] + dst), 16, 0, 0);                                \
        __builtin_amdgcn_global_load_lds((const AS1 void*)(gA + (koff) + 4096),   \
            (AS3 void*)(As[buf] + 4096 + dst), 16, 0, 0);                         \
        __builtin_amdgcn_global_load_lds((const AS1 void*)(gB + (koff)),          \
            (AS3 void*)(Bs[buf] + dst), 16, 0, 0);                                \
        __builtin_amdgcn_global_load_lds((const AS1 void*)(gB + (koff) + 4096),   \
            (AS3 void*)(Bs[buf] + 4096 + dst), 16, 0, 0);                         \
    } while (0)

// ------ kernel 2 (PRODUCTION, R15-exact): contended atomics into denom ------
__global__ __launch_bounds__(256) void gemm_denom_kernel(
        const unsigned char* __restrict__ znb, float* __restrict__ denom) {
    const int tr = blockIdx.x;
    const int tc = blockIdx.y;
    if (tc < tr) return;

    GEMM_BODY

    const bool offdiag = (tr != tc);
    float cs[4] = {0.f, 0.f, 0.f, 0.f};
    #pragma unroll
    for (int m = 0; m < 4; ++m) {
        #pragma unroll
        for (int reg = 0; reg < 4; ++reg) {
            const int rg = row0 + wr * 64 + m * 16 + kgrp * 4 + reg;
            float rs = 0.f;
            #pragma unroll
            for (int n = 0; n < 4; ++n) {
                const int cg = col0 + wc * 64 + n * 16 + r16;
                float e = __expf(acc[m][n][reg] * INV_T);
                if (rg == cg) e = 0.f;
                rs += e;
                cs[n] += e;
            }
            rs += __shfl_xor(rs, 1);
            rs += __shfl_xor(rs, 2);
            rs += __shfl_xor(rs, 4);
            rs += __shfl_xor(rs, 8);
            if (r16 == 0) atomicAdd(&denom[rg], rs);
        }
    }
    if (offdiag) {
        #pragma unroll
        for (int n = 0; n < 4; ++n) {
            cs[n] += __shfl_xor(cs[n], 16);
            cs[n] += __shfl_xor(cs[n], 32);
        }
        if (kgrp == 0) {
            #pragma unroll
            for (int n = 0; n < 4; ++n)
                atomicAdd(&denom[col0 + wc * 64 + n * 16 + r16], cs[n]);
        }
    }
}

// ------ probes: identical loop+epilogue, but targets are per-tile private ----
// slots (contention <=2 instead of ~65). MODE 0: atomicAdd; MODE 1: plain
// stores. Ppriv[(tr*64+tc)*128 + local] at ws [2,4) MB -- untouched by
// production. Output-irrelevant; exists purely for the rocprof A/B.
template<int MODE>
__global__ __launch_bounds__(256) void gemm_probe(
        const unsigned char* __restrict__ znb, float* __restrict__ Ppriv) {
    const int tr = blockIdx.x;
    const int tc = blockIdx.y;
    if (tc < tr) return;

    GEMM_BODY

    float* slot = Ppriv + ((size_t)tr * NTILE + tc) * 128;
    const bool offdiag = (tr != tc);
    float cs[4] = {0.f, 0.f, 0.f, 0.f};
    #pragma unroll
    for (int m = 0; m < 4; ++m) {
        #pragma unroll
        for (int reg = 0; reg < 4; ++reg) {
            const int rl = wr * 64 + m * 16 + kgrp * 4 + reg;
            float rs = 0.f;
            #pragma unroll
            for (int n = 0; n < 4; ++n) {
                const int cg = col0 + wc * 64 + n * 16 + r16;
                float e = __expf(acc[m][n][reg] * INV_T);
                if (row0 + rl == cg) e = 0.f;
                rs += e;
                cs[n] += e;
            }
            rs += __shfl_xor(rs, 1);
            rs += __shfl_xor(rs, 2);
            rs += __shfl_xor(rs, 4);
            rs += __shfl_xor(rs, 8);
            if (r16 == 0) {
                if constexpr (MODE == 0) atomicAdd(&slot[rl], rs);
                else                     slot[rl] = rs;
            }
        }
    }
    if (offdiag) {
        #pragma unroll
        for (int n = 0; n < 4; ++n) {
            cs[n] += __shfl_xor(cs[n], 16);
            cs[n] += __shfl_xor(cs[n], 32);
        }
        if (kgrp == 0) {
            #pragma unroll
            for (int n = 0; n < 4; ++n) {
                const int cl = wc * 64 + n * 16 + r16;
                if constexpr (MODE == 0) atomicAdd(&slot[cl], cs[n]);
                else                     slot[cl] = cs[n];
            }
        }
    }
}

// ------ kernel 3 (R15-exact): parallel final loss reduction ------
__global__ __launch_bounds__(1024) void final_kernel(
        const float* __restrict__ sim_pos, const float* __restrict__ denom,
        float* __restrict__ facc, int* __restrict__ ftick,
        float* __restrict__ out) {
    const int tid = threadIdx.x;
    const int gid = blockIdx.x * 1024 + tid;
    float s = sim_pos[gid] - __logf(denom[gid]);
    #pragma unroll
    for (int off = 32; off; off >>= 1) s += __shfl_down(s, off);
    __shared__ float red[16];
    const int wid = tid >> 6, lane = tid & 63;
    if (lane == 0) red[wid] = s;
    __syncthreads();
    if (tid == 0) {
        float bs = 0.f;
        #pragma unroll
        for (int w = 0; w < 16; ++w) bs += red[w];
        atomicAdd(facc, bs);
        __threadfence();
        const int t = atomicAdd(ftick, 1);
        if (t == 7) {
            const float tot = atomicAdd(facc, 0.0f);
            out[0] = -tot / (float)TWO_N;
        }
    }
}

extern "C" void kernel_launch(void* const* d_in, const int* in_sizes, int n_in,
                              void* d_out, int out_size, void* d_ws, size_t ws_size,
                              hipStream_t stream) {
    const float* z_i = (const float*)d_in[0];
    const float* z_j = (const float*)d_in[1];
    float* out = (float*)d_out;

    unsigned char* znb = (unsigned char*)d_ws;                      // [0, 2 MB)
    float* Ppriv   = (float*)((char*)d_ws + (2u << 20));            // [2, 4 MB): probe scratch
    float* sim_pos = (float*)((char*)d_ws + (4u << 20));            // R15-proven zone
    float* denom   = sim_pos + TWO_N;
    float* facc    = denom + TWO_N;
    int*   ftick   = (int*)(facc + 1);

    norm_pos_kernel<<<NHALF / 4, 256, 0, stream>>>(z_i, z_j, znb, sim_pos, denom,
                                                   facc, ftick);
    dim3 grid(NTILE, NTILE);
    gemm_denom_kernel<<<grid, 256, 0, stream>>>(znb, denom);
    final_kernel<<<TWO_N / 1024, 1024, 0, stream>>>(sim_pos, denom, facc, ftick, out);

    // ---- probes: full-scale A/B on epilogue-atomic contention ----
    gemm_probe<0><<<grid, 256, 0, stream>>>(znb, Ppriv);  // uncontended atomics
    gemm_probe<1><<<grid, 256, 0, stream>>>(znb, Ppriv);  // plain stores
}